// Round 6
// baseline (112.238 us; speedup 1.0000x reference)
//
#include <hip/hip_runtime.h>
#include <hip/hip_bf16.h>

typedef __bf16 bf16x8 __attribute__((ext_vector_type(8)));
typedef float f32x4 __attribute__((ext_vector_type(4)));

#define HDIM 4096
#define EDIM 64
#define KBLK 128        // 4096 / 32
#define CH 4            // kb-steps per staged B chunk (16 KB)
#define NCH (KBLK/CH)   // 32 chunks

// ---------------------------------------------------------------------------
// Kernel 1: coalesced repack of W into MFMA B-frag layout (UNnormalized bf16)
// + per-block per-column sum-of-squares partials (fp32).
// Wp element index for B[k][e]: nt=e>>4, col=e&15, kb=k>>5, g=(k>>3)&3, j=k&7
//   -> ((nt*KBLK + kb)*64 + col + 16*g)*8 + j
// ---------------------------------------------------------------------------
__global__ __launch_bounds__(256) void pack_w_kernel(const float* __restrict__ W,
                                                     __bf16* __restrict__ Wp,
                                                     float* __restrict__ partial) {
  const int b = blockIdx.x;        // 64 blocks x 64 rows of W
  const int t = threadIdx.x;
  const int e = t & 63;
  const int nt = e >> 4, col = e & 15;
  __shared__ float red[256];
  float s = 0.f;
  const int base = b * 64 * 64;
#pragma unroll
  for (int i = 0; i < 16; ++i) {
    int flat = base + i * 256 + t;         // coalesced
    float v = W[flat];
    s = fmaf(v, v, s);
    int r = flat >> 6;                     // k index
    int kb = r >> 5, g = (r >> 3) & 3, j = r & 7;
    Wp[(size_t)((nt * KBLK + kb) * 64 + col + 16 * g) * 8 + j] = (__bf16)v;
  }
  red[t] = s;
  __syncthreads();
  if (t < 64)
    partial[b * 64 + t] = red[t] + red[t + 64] + red[t + 128] + red[t + 192];
}

// ---------------------------------------------------------------------------
// Kernel 2: fused norm_h @ (Wp * invw) + epilogue.
// ONE block per CU (grid 256): 4 waves x 16 rows = 64 rows, full K per wave.
// B (512 KB packed) is streamed ONCE per CU through double-buffered LDS
// chunks (CH=4 kb-steps = 16 KB): reg-staged loads at chunk top, ds_write
// just before the barrier. Cuts per-CU VMEM instrs 3100 -> ~1800 (the
// measured limiter: ~70 cy per VMEM instr per CU regardless of occupancy).
// A: direct global->reg (R1 dataflow). All chunk VMEM consumed before the
// barrier, so the __syncthreads vmcnt-drain is cheap.
// A-frag: lane l holds h[wrow+(l&15)][kb*32 + (l>>4)*8 + j]  (fp32->bf16).
// C/D layout (m89): lane l, reg r -> row (l>>4)*4+r, col l&15.
// ---------------------------------------------------------------------------
__global__ __launch_bounds__(256, 1) void gate_main_kernel(
    const float* __restrict__ H, const __bf16* __restrict__ Wp,
    const float* __restrict__ G, const float* __restrict__ partial,
    float* __restrict__ out, size_t third) {
  const int lane = threadIdx.x & 63;
  const int w = threadIdx.x >> 6;        // wave id = row-group id
  const int m = lane & 15;
  const int g = lane >> 4;
  const int row0 = blockIdx.x * 64;
  const int wrow = row0 + w * 16;        // this wave's 16 rows

  __shared__ __align__(16) char ldsB[2][CH * 4 * 1024];   // 32 KB dbuf
  __shared__ float lds_invw[64];

  // W-column inv-norms from pack partials (once per block, tiny)
  if (threadIdx.x < 64) {
    float cs = 0.f;
#pragma unroll 8
    for (int i = 0; i < 64; ++i) cs += partial[i * 64 + threadIdx.x];
    lds_invw[threadIdx.x] = 1.0f / fmaxf(sqrtf(cs), 1e-12f);
  }

  const char* WpB = (const char*)Wp;
  const int lb = lane * 16;

  // prologue: stage B chunk 0 (wave w stages step-slot w, all 4 nt)
#pragma unroll
  for (int q = 0; q < 4; ++q) {
    float4 br = *(const float4*)(WpB + ((size_t)(q * KBLK + w) << 10) + lb);
    *(float4*)(&ldsB[0][(w * 4 + q) * 1024 + lb]) = br;
  }
  __syncthreads();

  const float* hp = H + (size_t)(wrow + m) * HDIM + g * 8;

  f32x4 acc[4] = {};
  float ssq0 = 0.f, ssq1 = 0.f;

  for (int c = 0; c < NCH; ++c) {
    // issue next chunk's B loads early (latency hidden under this chunk)
    float4 breg[4];
    if (c + 1 < NCH) {
#pragma unroll
      for (int q = 0; q < 4; ++q)
        breg[q] = *(const float4*)(
            WpB + ((size_t)(q * KBLK + (c + 1) * CH + w) << 10) + lb);
    }

    const char* bufc = ldsB[c & 1];
#pragma unroll
    for (int s = 0; s < CH; ++s) {
      const int kb = c * CH + s;
      float4 a0 = *(const float4*)(hp + (size_t)kb * 32);
      float4 a1 = *(const float4*)(hp + (size_t)kb * 32 + 4);

      bf16x8 bfr[4];
#pragma unroll
      for (int nt = 0; nt < 4; ++nt)
        bfr[nt] = *(const bf16x8*)(bufc + (s * 4 + nt) * 1024 + lb);

      bf16x8 af;
      af[0] = (__bf16)a0.x; af[1] = (__bf16)a0.y;
      af[2] = (__bf16)a0.z; af[3] = (__bf16)a0.w;
      af[4] = (__bf16)a1.x; af[5] = (__bf16)a1.y;
      af[6] = (__bf16)a1.z; af[7] = (__bf16)a1.w;

      ssq0 = fmaf(a0.x, a0.x, ssq0); ssq1 = fmaf(a0.y, a0.y, ssq1);
      ssq0 = fmaf(a0.z, a0.z, ssq0); ssq1 = fmaf(a0.w, a0.w, ssq1);
      ssq0 = fmaf(a1.x, a1.x, ssq0); ssq1 = fmaf(a1.y, a1.y, ssq1);
      ssq0 = fmaf(a1.z, a1.z, ssq0); ssq1 = fmaf(a1.w, a1.w, ssq1);

#pragma unroll
      for (int nt = 0; nt < 4; ++nt)
        acc[nt] = __builtin_amdgcn_mfma_f32_16x16x32_bf16(af, bfr[nt], acc[nt], 0, 0, 0);
    }

    // commit next chunk to the other LDS buffer, then sync
    if (c + 1 < NCH) {
      char* bufn = ldsB[(c + 1) & 1];
#pragma unroll
      for (int q = 0; q < 4; ++q)
        *(float4*)(bufn + (w * 4 + q) * 1024 + lb) = breg[q];
    }
    __syncthreads();
  }

  // ---- per-wave epilogue (no cross-wave combine: each wave owns its rows)
  float ssq = ssq0 + ssq1;
  ssq += __shfl_xor(ssq, 16, 64);
  ssq += __shfl_xor(ssq, 32, 64);
  float inv = 1.0f / fmaxf(sqrtf(ssq), 1e-12f);
  float invr[4];
#pragma unroll
  for (int r = 0; r < 4; ++r) invr[r] = __shfl(inv, g * 4 + r, 64);

#pragma unroll
  for (int nt = 0; nt < 4; ++nt) {
    const int e = nt * 16 + m;
    const float invw = lds_invw[e];
    const float sg = 1.0f / (1.0f + __expf(-G[e]));
#pragma unroll
    for (int r = 0; r < 4; ++r) {
      float raw = acc[nt][r] * invr[r] * invw;
      float sig = 1.0f / (1.0f + __expf(-raw));
      size_t idx = (size_t)(wrow + g * 4 + r) * EDIM + e;
      out[idx] = raw;
      out[idx + third] = sig;
      out[idx + 2 * third] = fmaxf(sig - sg, 0.0f);
    }
  }
}

extern "C" void kernel_launch(void* const* d_in, const int* in_sizes, int n_in,
                              void* d_out, int out_size, void* d_ws, size_t ws_size,
                              hipStream_t stream) {
  const float* H = (const float*)d_in[0];   // [B*S, 4096]
  const float* W = (const float*)d_in[1];   // [4096, 64]
  const float* G = (const float*)d_in[2];   // [64]
  float* out = (float*)d_out;               // 3 x [B*S, 64] concatenated
  __bf16* Wp = (__bf16*)d_ws;               // 512 KB packed (unnormalized) W
  float* partial = (float*)((char*)d_ws + 512 * 1024);  // 64 blocks x 64 cols

  int rows = in_sizes[0] / HDIM;            // 16384
  size_t third = (size_t)out_size / 3;      // 1048576

  pack_w_kernel<<<64, 256, 0, stream>>>(W, Wp, partial);
  gate_main_kernel<<<rows / 64, 256, 0, stream>>>(H, Wp, G, partial, out, third);
}

// Round 7
// 57.709 us; speedup vs baseline: 1.9449x; 1.9449x over previous
//
#include <hip/hip_runtime.h>
#include <hip/hip_bf16.h>

typedef __bf16 bf16x8 __attribute__((ext_vector_type(8)));
typedef float f32x4 __attribute__((ext_vector_type(4)));

#define HDIM 4096
#define EDIM 64
#define KBLK 128        // 4096 / 32
#define NW 8            // waves per block = K-split factor
#define KBW (KBLK/NW)   // 16 kb-steps per wave
#define NRG 4           // row-groups per wave (64 rows per block)

// ---------------------------------------------------------------------------
// Kernel 1: coalesced repack of W into MFMA B-frag layout (UNnormalized bf16)
// + per-block per-column sum-of-squares partials (fp32).
// Wp element index for B[k][e]: nt=e>>4, col=e&15, kb=k>>5, g=(k>>3)&3, j=k&7
//   -> ((nt*KBLK + kb)*64 + col + 16*g)*8 + j
// ---------------------------------------------------------------------------
__global__ __launch_bounds__(256) void pack_w_kernel(const float* __restrict__ W,
                                                     __bf16* __restrict__ Wp,
                                                     float* __restrict__ partial) {
  const int b = blockIdx.x;        // 64 blocks x 64 rows of W
  const int t = threadIdx.x;
  const int e = t & 63;
  const int nt = e >> 4, col = e & 15;
  __shared__ float red[256];
  float s = 0.f;
  const int base = b * 64 * 64;
#pragma unroll
  for (int i = 0; i < 16; ++i) {
    int flat = base + i * 256 + t;         // coalesced
    float v = W[flat];
    s = fmaf(v, v, s);
    int r = flat >> 6;                     // k index
    int kb = r >> 5, g = (r >> 3) & 3, j = r & 7;
    Wp[(size_t)((nt * KBLK + kb) * 64 + col + 16 * g) * 8 + j] = (__bf16)v;
  }
  red[t] = s;
  __syncthreads();
  if (t < 64)
    partial[b * 64 + t] = red[t] + red[t + 64] + red[t + 128] + red[t + 192];
}

// ---------------------------------------------------------------------------
// Kernel 2: fused norm_h @ (Wp * invw) + epilogue.
// 64 rows/block (grid 256 = 1 block/CU) to cut B L1-re-misses 4x (the
// MSHR-latency model's dominant reducible term). 8 waves (512 thr),
// K-split x8: wave w owns kb [w*16, w*16+16) for ALL 4 row-groups.
// Direct global->reg A loads (R1 dataflow), NO barriers in main loop,
// unroll keeps ~24 independent loads in flight per wave to fill MSHRs.
// A-frag: lane l holds h[rg*16+(l&15)][kb*32+(l>>4)*8+j]  (fp32->bf16).
// C/D layout (m89): lane l, reg r -> row (l>>4)*4+r, col l&15.
// Combine across waves through 128 KB LDS once at the end.
// ---------------------------------------------------------------------------
__global__ __launch_bounds__(512, 1) void gate_main_kernel(
    const float* __restrict__ H, const __bf16* __restrict__ Wp,
    const float* __restrict__ G, const float* __restrict__ partial,
    float* __restrict__ out, size_t third) {
  const int lane = threadIdx.x & 63;
  const int w = threadIdx.x >> 6;        // wave id = K-slice id, 0..7
  const int m = lane & 15;
  const int g = lane >> 4;
  const int row0 = blockIdx.x * 64;

  __shared__ float lds_acc[NRG][4][4][NW][64];  // rg, nt, reg, slice, lane: 128 KB
  __shared__ float lds_ssq[NW][64];             // slice, row
  __shared__ float lds_invw[64];

  // W-column inv-norms from pack partials (tiny, once per block)
  if (threadIdx.x < 64) {
    float cs = 0.f;
#pragma unroll 8
    for (int i = 0; i < 64; ++i) cs += partial[i * 64 + threadIdx.x];
    lds_invw[threadIdx.x] = 1.0f / fmaxf(sqrtf(cs), 1e-12f);
  }

  const int kb0 = w * KBW;
  const float* hp0 = H + (size_t)(row0 + 0 * 16 + m) * HDIM + kb0 * 32 + g * 8;
  const float* hp1 = hp0 + (size_t)16 * HDIM;
  const float* hp2 = hp0 + (size_t)32 * HDIM;
  const float* hp3 = hp0 + (size_t)48 * HDIM;
  const bf16x8* bbase = reinterpret_cast<const bf16x8*>(Wp) + lane;

  f32x4 acc[NRG][4] = {};
  float ssqa[NRG], ssqb[NRG];
#pragma unroll
  for (int rg = 0; rg < NRG; ++rg) { ssqa[rg] = 0.f; ssqb[rg] = 0.f; }

#pragma unroll 2
  for (int i = 0; i < KBW; ++i) {
    float4 a0[NRG], a1[NRG];
    a0[0] = *(const float4*)(hp0 + (size_t)i * 32);
    a1[0] = *(const float4*)(hp0 + (size_t)i * 32 + 4);
    a0[1] = *(const float4*)(hp1 + (size_t)i * 32);
    a1[1] = *(const float4*)(hp1 + (size_t)i * 32 + 4);
    a0[2] = *(const float4*)(hp2 + (size_t)i * 32);
    a1[2] = *(const float4*)(hp2 + (size_t)i * 32 + 4);
    a0[3] = *(const float4*)(hp3 + (size_t)i * 32);
    a1[3] = *(const float4*)(hp3 + (size_t)i * 32 + 4);

    bf16x8 bfr[4];
#pragma unroll
    for (int nt = 0; nt < 4; ++nt)
      bfr[nt] = bbase[(size_t)(nt * KBLK + kb0 + i) * 64];

#pragma unroll
    for (int rg = 0; rg < NRG; ++rg) {
      bf16x8 af;
      af[0] = (__bf16)a0[rg].x; af[1] = (__bf16)a0[rg].y;
      af[2] = (__bf16)a0[rg].z; af[3] = (__bf16)a0[rg].w;
      af[4] = (__bf16)a1[rg].x; af[5] = (__bf16)a1[rg].y;
      af[6] = (__bf16)a1[rg].z; af[7] = (__bf16)a1[rg].w;

      ssqa[rg] = fmaf(a0[rg].x, a0[rg].x, ssqa[rg]);
      ssqb[rg] = fmaf(a0[rg].y, a0[rg].y, ssqb[rg]);
      ssqa[rg] = fmaf(a0[rg].z, a0[rg].z, ssqa[rg]);
      ssqb[rg] = fmaf(a0[rg].w, a0[rg].w, ssqb[rg]);
      ssqa[rg] = fmaf(a1[rg].x, a1[rg].x, ssqa[rg]);
      ssqb[rg] = fmaf(a1[rg].y, a1[rg].y, ssqb[rg]);
      ssqa[rg] = fmaf(a1[rg].z, a1[rg].z, ssqa[rg]);
      ssqb[rg] = fmaf(a1[rg].w, a1[rg].w, ssqb[rg]);

#pragma unroll
      for (int nt = 0; nt < 4; ++nt)
        acc[rg][nt] = __builtin_amdgcn_mfma_f32_16x16x32_bf16(af, bfr[nt], acc[rg][nt], 0, 0, 0);
    }
  }

  // per-row partial ssq for this K-slice; write acc partials to LDS
#pragma unroll
  for (int rg = 0; rg < NRG; ++rg) {
    float ssq = ssqa[rg] + ssqb[rg];
    ssq += __shfl_xor(ssq, 16, 64);
    ssq += __shfl_xor(ssq, 32, 64);
    if (g == 0) lds_ssq[w][rg * 16 + m] = ssq;
#pragma unroll
    for (int nt = 0; nt < 4; ++nt)
#pragma unroll
      for (int r = 0; r < 4; ++r)
        lds_acc[rg][nt][r][w][lane] = acc[rg][nt][r];
  }
  __syncthreads();

  // Epilogue: lane = output column e; wave w handles rows {8w .. 8w+7},
  // each store is a full 256-B contiguous row per output tensor.
  {
    const int e = lane;
    const float invw = lds_invw[e];
    const float sg = 1.0f / (1.0f + __expf(-G[e]));
    const int nt = e >> 4;
#pragma unroll
    for (int rr = 0; rr < 8; ++rr) {
      const int R = w * 8 + rr;
      const int rg = R >> 4;
      const int r = R & 3;
      const int lsrc = (((R >> 2) & 3) << 4) | (e & 15);
      float st = 0.f, a = 0.f;
#pragma unroll
      for (int s = 0; s < NW; ++s) {
        st += lds_ssq[s][R];
        a += lds_acc[rg][nt][r][s][lsrc];
      }
      float invh = 1.0f / fmaxf(sqrtf(st), 1e-12f);
      float raw = a * invh * invw;
      float sig = 1.0f / (1.0f + __expf(-raw));
      size_t idx = (size_t)(row0 + R) * EDIM + e;
      out[idx] = raw;
      out[idx + third] = sig;
      out[idx + 2 * third] = fmaxf(sig - sg, 0.0f);
    }
  }
}

extern "C" void kernel_launch(void* const* d_in, const int* in_sizes, int n_in,
                              void* d_out, int out_size, void* d_ws, size_t ws_size,
                              hipStream_t stream) {
  const float* H = (const float*)d_in[0];   // [B*S, 4096]
  const float* W = (const float*)d_in[1];   // [4096, 64]
  const float* G = (const float*)d_in[2];   // [64]
  float* out = (float*)d_out;               // 3 x [B*S, 64] concatenated
  __bf16* Wp = (__bf16*)d_ws;               // 512 KB packed (unnormalized) W
  float* partial = (float*)((char*)d_ws + 512 * 1024);  // 64 blocks x 64 cols

  int rows = in_sizes[0] / HDIM;            // 16384
  size_t third = (size_t)out_size / 3;      // 1048576

  pack_w_kernel<<<64, 256, 0, stream>>>(W, Wp, partial);
  gate_main_kernel<<<rows / 64, 512, 0, stream>>>(H, Wp, G, partial, out, third);
}